// Round 4
// baseline (718.916 us; speedup 1.0000x reference)
//
#include <hip/hip_runtime.h>
#include <math.h>

#define B_ 32
#define S_ 4096
#define H_ 1024
#define WIN_ 10

// -------- Kernel 1: proj[b][h] = sum_k dec[b][k] * W[h][k] ------------------
// One wave per h (grid 256 x 4 waves). Lanes split K; W row loaded once into
// 16 regs/lane; dec re-read per b from L2 (128 KB total, hot).
__global__ __launch_bounds__(256) void proj_kernel(
    const float* __restrict__ dec, const float* __restrict__ W,
    float* __restrict__ proj)
{
    const int lane = threadIdx.x & 63;
    const int wave = threadIdx.x >> 6;
    const int h = blockIdx.x * 4 + wave;
    const float4* __restrict__ W4 = (const float4*)(W + (size_t)h * H_);
    const float4 w0 = W4[lane];
    const float4 w1 = W4[lane + 64];
    const float4 w2 = W4[lane + 128];
    const float4 w3 = W4[lane + 192];
    #pragma unroll 4
    for (int b = 0; b < B_; ++b) {
        const float4* __restrict__ d4 = (const float4*)(dec + (size_t)b * H_);
        float4 a0 = d4[lane];
        float4 a1 = d4[lane + 64];
        float4 a2 = d4[lane + 128];
        float4 a3 = d4[lane + 192];
        float p = w0.x*a0.x + w0.y*a0.y + w0.z*a0.z + w0.w*a0.w
                + w1.x*a1.x + w1.y*a1.y + w1.z*a1.z + w1.w*a1.w
                + w2.x*a2.x + w2.y*a2.y + w2.z*a2.z + w2.w*a2.w
                + w3.x*a3.x + w3.y*a3.y + w3.z*a3.z + w3.w*a3.w;
        #pragma unroll
        for (int off = 32; off > 0; off >>= 1)
            p += __shfl_xor(p, off, 64);
        if (lane == 0) proj[(size_t)b * H_ + h] = p;
    }
}

// -------- Kernel 2: energy[b][s] = enc[b,s,:] . proj[b,:] -------------------
// THE memory-bound kernel: streams all 512 MB of enc exactly once.
// 2048 blocks x 256 thr = 8 blocks/CU. Wave handles 16 consecutive rows;
// lanes stripe the 4 KB row as float4 (1 KB per load instruction).
__global__ __launch_bounds__(256) void energy_kernel(
    const float* __restrict__ enc, const float* __restrict__ proj,
    float* __restrict__ energy)
{
    const int lane = threadIdx.x & 63;
    const int wave = threadIdx.x >> 6;
    const int b = blockIdx.x >> 6;
    const int s0 = ((blockIdx.x & 63) << 6) + (wave << 4);
    const float4* __restrict__ p4 = (const float4*)(proj + (size_t)b * H_);
    const float4 q0 = p4[lane];
    const float4 q1 = p4[lane + 64];
    const float4 q2 = p4[lane + 128];
    const float4 q3 = p4[lane + 192];
    #pragma unroll 4
    for (int r = 0; r < 16; ++r) {
        const int s = s0 + r;
        const float4* __restrict__ e4 =
            (const float4*)(enc + ((size_t)b * S_ + s) * H_);
        float4 a0 = e4[lane];
        float4 a1 = e4[lane + 64];
        float4 a2 = e4[lane + 128];
        float4 a3 = e4[lane + 192];
        float p = q0.x*a0.x + q0.y*a0.y + q0.z*a0.z + q0.w*a0.w
                + q1.x*a1.x + q1.y*a1.y + q1.z*a1.z + q1.w*a1.w
                + q2.x*a2.x + q2.y*a2.y + q2.z*a2.z + q2.w*a2.w
                + q3.x*a3.x + q3.y*a3.y + q3.z*a3.z + q3.w*a3.w;
        #pragma unroll
        for (int off = 32; off > 0; off >>= 1)
            p += __shfl_xor(p, off, 64);
        if (lane == 0) energy[(size_t)b * S_ + s] = p;
    }
}

// -------- Kernel 3: masked softmax + sparse context gather ------------------
// One block per batch. Multiplicative -1e10 mask (faithful to reference),
// exp underflows to exactly 0.0 outside a ~87-wide band below the max (same
// as numpy f32), so context only needs the p>0 positions (typically 1).
__global__ __launch_bounds__(256) void softmax_ctx_kernel(
    const float* __restrict__ enc, const float* __restrict__ energy,
    const int* __restrict__ pos_p,
    float* __restrict__ out_ctx, float* __restrict__ out_att)
{
    __shared__ float sp[S_];                 // masked energy, then p
    __shared__ unsigned short slist[S_];     // indices with p > 0
    __shared__ float sred[8];
    __shared__ int scnt;
    const int tid = threadIdx.x;
    const int b = blockIdx.x;
    const int pos = *pos_p;
    const int lo = pos - WIN_ < 0 ? 0 : pos - WIN_;
    const int hi = pos + WIN_ - 1 > S_ - 1 ? S_ - 1 : pos + WIN_ - 1;

    float lmax = -INFINITY;
    for (int s = tid; s < S_; s += 256) {
        float e = energy[(size_t)b * S_ + s];
        float m = (s >= lo && s <= hi) ? e : -1e10f * e;
        sp[s] = m;
        lmax = fmaxf(lmax, m);
    }
    #pragma unroll
    for (int off = 32; off > 0; off >>= 1)
        lmax = fmaxf(lmax, __shfl_xor(lmax, off, 64));
    if ((tid & 63) == 0) sred[tid >> 6] = lmax;
    if (tid == 0) scnt = 0;
    __syncthreads();
    const float gmax = fmaxf(fmaxf(sred[0], sred[1]), fmaxf(sred[2], sred[3]));

    float lsum = 0.f;
    for (int s = tid; s < S_; s += 256) {
        float p = expf(sp[s] - gmax);
        sp[s] = p;
        lsum += p;
        if (p > 0.f) {
            int i = atomicAdd(&scnt, 1);
            slist[i] = (unsigned short)s;   // capacity S_ -> cannot overflow
        }
    }
    #pragma unroll
    for (int off = 32; off > 0; off >>= 1)
        lsum += __shfl_xor(lsum, off, 64);
    if ((tid & 63) == 0) sred[4 + (tid >> 6)] = lsum;
    __syncthreads();
    const float gsum = sred[4] + sred[5] + sred[6] + sred[7];
    const float inv = 1.0f / gsum;

    for (int s = tid; s < S_; s += 256)
        out_att[(size_t)b * S_ + s] = sp[s] * inv;

    // context[b, h] = sum over contributing s of a_s * enc[b,s,h]
    const int cnt = scnt;
    float4 acc = make_float4(0.f, 0.f, 0.f, 0.f);
    for (int j = 0; j < cnt; ++j) {
        const int s = slist[j];
        const float a = sp[s] * inv;
        const float4 v =
            ((const float4*)(enc + ((size_t)b * S_ + s) * H_))[tid];
        acc.x += a * v.x; acc.y += a * v.y;
        acc.z += a * v.z; acc.w += a * v.w;
    }
    ((float4*)(out_ctx + (size_t)b * H_))[tid] = acc;
}

extern "C" void kernel_launch(void* const* d_in, const int* in_sizes, int n_in,
                              void* d_out, int out_size, void* d_ws, size_t ws_size,
                              hipStream_t stream) {
    const float* dec = (const float*)d_in[0];   // [32,1024]
    const float* enc = (const float*)d_in[1];   // [32,4096,1024]
    const float* W   = (const float*)d_in[2];   // [1024,1024]
    const int*   pos = (const int*)d_in[3];     // scalar

    float* out      = (float*)d_out;
    float* out_ctx  = out;                      // [32,1,1024] -> 32768
    float* out_att  = out + (size_t)B_ * H_;    // [32,4096,1] -> 131072

    float* proj   = (float*)d_ws;               // 32768 floats (128 KB)
    float* energy = proj + (size_t)B_ * H_;     // 131072 floats (512 KB)

    proj_kernel<<<256, 256, 0, stream>>>(dec, W, proj);
    energy_kernel<<<2048, 256, 0, stream>>>(enc, proj, energy);
    softmax_ctx_kernel<<<32, 256, 0, stream>>>(enc, energy, pos, out_ctx, out_att);
}

// Round 5
// 718.291 us; speedup vs baseline: 1.0009x; 1.0009x over previous
//
#include <hip/hip_runtime.h>
#include <math.h>

#define B_ 32
#define S_ 4096
#define H_ 1024
#define WIN_ 10

// -------- Kernel 1: proj[b][h] = sum_k dec[b][k] * W[h][k] ------------------
// One wave per h (grid 256 x 4 waves). Lanes split K; W row loaded once into
// 16 regs/lane; dec re-read per b from L2 (128 KB total, hot).
__global__ __launch_bounds__(256) void proj_kernel(
    const float* __restrict__ dec, const float* __restrict__ W,
    float* __restrict__ proj)
{
    const int lane = threadIdx.x & 63;
    const int wave = threadIdx.x >> 6;
    const int h = blockIdx.x * 4 + wave;
    const float4* __restrict__ W4 = (const float4*)(W + (size_t)h * H_);
    const float4 w0 = W4[lane];
    const float4 w1 = W4[lane + 64];
    const float4 w2 = W4[lane + 128];
    const float4 w3 = W4[lane + 192];
    #pragma unroll 4
    for (int b = 0; b < B_; ++b) {
        const float4* __restrict__ d4 = (const float4*)(dec + (size_t)b * H_);
        float4 a0 = d4[lane];
        float4 a1 = d4[lane + 64];
        float4 a2 = d4[lane + 128];
        float4 a3 = d4[lane + 192];
        float p = w0.x*a0.x + w0.y*a0.y + w0.z*a0.z + w0.w*a0.w
                + w1.x*a1.x + w1.y*a1.y + w1.z*a1.z + w1.w*a1.w
                + w2.x*a2.x + w2.y*a2.y + w2.z*a2.z + w2.w*a2.w
                + w3.x*a3.x + w3.y*a3.y + w3.z*a3.z + w3.w*a3.w;
        #pragma unroll
        for (int off = 32; off > 0; off >>= 1)
            p += __shfl_xor(p, off, 64);
        if (lane == 0) proj[(size_t)b * H_ + h] = p;
    }
}

// -------- Kernel 2: energy[b][s] = enc[b,s,:] . proj[b,:] -------------------
// THE memory-bound kernel: streams all 512 MB of enc exactly once.
// 2048 blocks x 256 thr = 8 blocks/CU. Wave handles 16 consecutive rows;
// lanes stripe the 4 KB row as float4 (1 KB per load instruction).
__global__ __launch_bounds__(256) void energy_kernel(
    const float* __restrict__ enc, const float* __restrict__ proj,
    float* __restrict__ energy)
{
    const int lane = threadIdx.x & 63;
    const int wave = threadIdx.x >> 6;
    const int b = blockIdx.x >> 6;
    const int s0 = ((blockIdx.x & 63) << 6) + (wave << 4);
    const float4* __restrict__ p4 = (const float4*)(proj + (size_t)b * H_);
    const float4 q0 = p4[lane];
    const float4 q1 = p4[lane + 64];
    const float4 q2 = p4[lane + 128];
    const float4 q3 = p4[lane + 192];
    #pragma unroll 4
    for (int r = 0; r < 16; ++r) {
        const int s = s0 + r;
        const float4* __restrict__ e4 =
            (const float4*)(enc + ((size_t)b * S_ + s) * H_);
        float4 a0 = e4[lane];
        float4 a1 = e4[lane + 64];
        float4 a2 = e4[lane + 128];
        float4 a3 = e4[lane + 192];
        float p = q0.x*a0.x + q0.y*a0.y + q0.z*a0.z + q0.w*a0.w
                + q1.x*a1.x + q1.y*a1.y + q1.z*a1.z + q1.w*a1.w
                + q2.x*a2.x + q2.y*a2.y + q2.z*a2.z + q2.w*a2.w
                + q3.x*a3.x + q3.y*a3.y + q3.z*a3.z + q3.w*a3.w;
        #pragma unroll
        for (int off = 32; off > 0; off >>= 1)
            p += __shfl_xor(p, off, 64);
        if (lane == 0) energy[(size_t)b * S_ + s] = p;
    }
}

// -------- Kernel 3: masked softmax + sparse context gather ------------------
// One block per batch. Multiplicative -1e10 mask (faithful to reference),
// exp underflows to exactly 0.0 outside a ~87-wide band below the max (same
// as numpy f32), so context only needs the p>0 positions (typically 1).
__global__ __launch_bounds__(256) void softmax_ctx_kernel(
    const float* __restrict__ enc, const float* __restrict__ energy,
    const int* __restrict__ pos_p,
    float* __restrict__ out_ctx, float* __restrict__ out_att)
{
    __shared__ float sp[S_];                 // masked energy, then p
    __shared__ unsigned short slist[S_];     // indices with p > 0
    __shared__ float sred[8];
    __shared__ int scnt;
    const int tid = threadIdx.x;
    const int b = blockIdx.x;
    const int pos = *pos_p;
    const int lo = pos - WIN_ < 0 ? 0 : pos - WIN_;
    const int hi = pos + WIN_ - 1 > S_ - 1 ? S_ - 1 : pos + WIN_ - 1;

    float lmax = -INFINITY;
    for (int s = tid; s < S_; s += 256) {
        float e = energy[(size_t)b * S_ + s];
        float m = (s >= lo && s <= hi) ? e : -1e10f * e;
        sp[s] = m;
        lmax = fmaxf(lmax, m);
    }
    #pragma unroll
    for (int off = 32; off > 0; off >>= 1)
        lmax = fmaxf(lmax, __shfl_xor(lmax, off, 64));
    if ((tid & 63) == 0) sred[tid >> 6] = lmax;
    if (tid == 0) scnt = 0;
    __syncthreads();
    const float gmax = fmaxf(fmaxf(sred[0], sred[1]), fmaxf(sred[2], sred[3]));

    float lsum = 0.f;
    for (int s = tid; s < S_; s += 256) {
        float p = expf(sp[s] - gmax);
        sp[s] = p;
        lsum += p;
        if (p > 0.f) {
            int i = atomicAdd(&scnt, 1);
            slist[i] = (unsigned short)s;   // capacity S_ -> cannot overflow
        }
    }
    #pragma unroll
    for (int off = 32; off > 0; off >>= 1)
        lsum += __shfl_xor(lsum, off, 64);
    if ((tid & 63) == 0) sred[4 + (tid >> 6)] = lsum;
    __syncthreads();
    const float gsum = sred[4] + sred[5] + sred[6] + sred[7];
    const float inv = 1.0f / gsum;

    for (int s = tid; s < S_; s += 256)
        out_att[(size_t)b * S_ + s] = sp[s] * inv;

    // context[b, h] = sum over contributing s of a_s * enc[b,s,h]
    const int cnt = scnt;
    float4 acc = make_float4(0.f, 0.f, 0.f, 0.f);
    for (int j = 0; j < cnt; ++j) {
        const int s = slist[j];
        const float a = sp[s] * inv;
        const float4 v =
            ((const float4*)(enc + ((size_t)b * S_ + s) * H_))[tid];
        acc.x += a * v.x; acc.y += a * v.y;
        acc.z += a * v.z; acc.w += a * v.w;
    }
    ((float4*)(out_ctx + (size_t)b * H_))[tid] = acc;
}

extern "C" void kernel_launch(void* const* d_in, const int* in_sizes, int n_in,
                              void* d_out, int out_size, void* d_ws, size_t ws_size,
                              hipStream_t stream) {
    const float* dec = (const float*)d_in[0];   // [32,1024]
    const float* enc = (const float*)d_in[1];   // [32,4096,1024]
    const float* W   = (const float*)d_in[2];   // [1024,1024]
    const int*   pos = (const int*)d_in[3];     // scalar

    float* out      = (float*)d_out;
    float* out_ctx  = out;                      // [32,1,1024] -> 32768
    float* out_att  = out + (size_t)B_ * H_;    // [32,4096,1] -> 131072

    float* proj   = (float*)d_ws;               // 32768 floats (128 KB)
    float* energy = proj + (size_t)B_ * H_;     // 131072 floats (512 KB)

    proj_kernel<<<256, 256, 0, stream>>>(dec, W, proj);
    energy_kernel<<<2048, 256, 0, stream>>>(enc, proj, energy);
    softmax_ctx_kernel<<<32, 256, 0, stream>>>(enc, energy, pos, out_ctx, out_att);
}

// Round 6
// 715.216 us; speedup vs baseline: 1.0052x; 1.0043x over previous
//
#include <hip/hip_runtime.h>
#include <math.h>

#define B_ 32
#define S_ 4096
#define H_ 1024
#define WIN_ 10

// -------- Kernel 1: proj[b][h] = sum_k dec[b][k] * W[h][k] ------------------
// One wave per h (grid 256 x 4 waves). Lanes split K; W row loaded once into
// 16 regs/lane; dec re-read per b from L2 (128 KB total, hot).
__global__ __launch_bounds__(256) void proj_kernel(
    const float* __restrict__ dec, const float* __restrict__ W,
    float* __restrict__ proj)
{
    const int lane = threadIdx.x & 63;
    const int wave = threadIdx.x >> 6;
    const int h = blockIdx.x * 4 + wave;
    const float4* __restrict__ W4 = (const float4*)(W + (size_t)h * H_);
    const float4 w0 = W4[lane];
    const float4 w1 = W4[lane + 64];
    const float4 w2 = W4[lane + 128];
    const float4 w3 = W4[lane + 192];
    #pragma unroll 4
    for (int b = 0; b < B_; ++b) {
        const float4* __restrict__ d4 = (const float4*)(dec + (size_t)b * H_);
        float4 a0 = d4[lane];
        float4 a1 = d4[lane + 64];
        float4 a2 = d4[lane + 128];
        float4 a3 = d4[lane + 192];
        float p = w0.x*a0.x + w0.y*a0.y + w0.z*a0.z + w0.w*a0.w
                + w1.x*a1.x + w1.y*a1.y + w1.z*a1.z + w1.w*a1.w
                + w2.x*a2.x + w2.y*a2.y + w2.z*a2.z + w2.w*a2.w
                + w3.x*a3.x + w3.y*a3.y + w3.z*a3.z + w3.w*a3.w;
        #pragma unroll
        for (int off = 32; off > 0; off >>= 1)
            p += __shfl_xor(p, off, 64);
        if (lane == 0) proj[(size_t)b * H_ + h] = p;
    }
}

// -------- Kernel 2: energy[b][s] = enc[b,s,:] . proj[b,:] -------------------
// Streams all 512 MB of enc exactly once. 2048 blocks x 256 thr.
// Each wave owns 16 consecutive rows, processed as 4 tiles of 4 rows.
// Within a tile the 4 rows' load->FMA->shfl chains are interleaved, so no
// single dependency chain is on the critical path (4-wide latency hiding).
// VGPR ~52 -> launch_bounds(256,6) gives >=24 waves/CU without spill risk.
__global__ __launch_bounds__(256, 6) void energy_kernel(
    const float* __restrict__ enc, const float* __restrict__ proj,
    float* __restrict__ energy)
{
    const int lane = threadIdx.x & 63;
    const int wid  = (blockIdx.x << 2) | (threadIdx.x >> 6);  // 0..8191
    const int b    = wid >> 8;                 // 256 waves per batch
    const int s0   = (wid & 255) << 4;         // 16 rows per wave

    const float4* __restrict__ p4 = (const float4*)(proj + (size_t)b * H_);
    float4 qq[4];
    #pragma unroll
    for (int hc = 0; hc < 4; ++hc) qq[hc] = p4[lane + (hc << 6)];

    const float4* __restrict__ base =
        (const float4*)(enc + ((size_t)b * S_ + s0) * H_);
    float* __restrict__ eout = energy + (size_t)b * S_ + s0;

    #pragma unroll
    for (int t = 0; t < 16; t += 4) {
        const float4* __restrict__ r0 = base + (size_t)(t + 0) * 256;
        const float4* __restrict__ r1 = base + (size_t)(t + 1) * 256;
        const float4* __restrict__ r2 = base + (size_t)(t + 2) * 256;
        const float4* __restrict__ r3 = base + (size_t)(t + 3) * 256;
        float c0 = 0.f, c1 = 0.f, c2 = 0.f, c3 = 0.f;
        #pragma unroll
        for (int hc = 0; hc < 4; ++hc) {
            const int idx = lane + (hc << 6);
            const float4 v0 = r0[idx];
            const float4 v1 = r1[idx];
            const float4 v2 = r2[idx];
            const float4 v3 = r3[idx];
            const float4 q = qq[hc];
            c0 += v0.x*q.x + v0.y*q.y + v0.z*q.z + v0.w*q.w;
            c1 += v1.x*q.x + v1.y*q.y + v1.z*q.z + v1.w*q.w;
            c2 += v2.x*q.x + v2.y*q.y + v2.z*q.z + v2.w*q.w;
            c3 += v3.x*q.x + v3.y*q.y + v3.z*q.z + v3.w*q.w;
        }
        #pragma unroll
        for (int off = 32; off > 0; off >>= 1) {
            c0 += __shfl_xor(c0, off, 64);
            c1 += __shfl_xor(c1, off, 64);
            c2 += __shfl_xor(c2, off, 64);
            c3 += __shfl_xor(c3, off, 64);
        }
        if (lane == 0) {
            eout[t + 0] = c0;
            eout[t + 1] = c1;
            eout[t + 2] = c2;
            eout[t + 3] = c3;
        }
    }
}

// -------- Kernel 3: masked softmax + sparse context gather ------------------
// One block per batch. Multiplicative -1e10 mask (faithful to reference),
// exp underflows to exactly 0.0 outside a ~87-wide band below the max (same
// as numpy f32), so context only needs the p>0 positions (typically 1).
__global__ __launch_bounds__(256) void softmax_ctx_kernel(
    const float* __restrict__ enc, const float* __restrict__ energy,
    const int* __restrict__ pos_p,
    float* __restrict__ out_ctx, float* __restrict__ out_att)
{
    __shared__ float sp[S_];                 // masked energy, then p
    __shared__ unsigned short slist[S_];     // indices with p > 0
    __shared__ float sred[8];
    __shared__ int scnt;
    const int tid = threadIdx.x;
    const int b = blockIdx.x;
    const int pos = *pos_p;
    const int lo = pos - WIN_ < 0 ? 0 : pos - WIN_;
    const int hi = pos + WIN_ - 1 > S_ - 1 ? S_ - 1 : pos + WIN_ - 1;

    float lmax = -INFINITY;
    for (int s = tid; s < S_; s += 256) {
        float e = energy[(size_t)b * S_ + s];
        float m = (s >= lo && s <= hi) ? e : -1e10f * e;
        sp[s] = m;
        lmax = fmaxf(lmax, m);
    }
    #pragma unroll
    for (int off = 32; off > 0; off >>= 1)
        lmax = fmaxf(lmax, __shfl_xor(lmax, off, 64));
    if ((tid & 63) == 0) sred[tid >> 6] = lmax;
    if (tid == 0) scnt = 0;
    __syncthreads();
    const float gmax = fmaxf(fmaxf(sred[0], sred[1]), fmaxf(sred[2], sred[3]));

    float lsum = 0.f;
    for (int s = tid; s < S_; s += 256) {
        float p = expf(sp[s] - gmax);
        sp[s] = p;
        lsum += p;
        if (p > 0.f) {
            int i = atomicAdd(&scnt, 1);
            slist[i] = (unsigned short)s;   // capacity S_ -> cannot overflow
        }
    }
    #pragma unroll
    for (int off = 32; off > 0; off >>= 1)
        lsum += __shfl_xor(lsum, off, 64);
    if ((tid & 63) == 0) sred[4 + (tid >> 6)] = lsum;
    __syncthreads();
    const float gsum = sred[4] + sred[5] + sred[6] + sred[7];
    const float inv = 1.0f / gsum;

    for (int s = tid; s < S_; s += 256)
        out_att[(size_t)b * S_ + s] = sp[s] * inv;

    // context[b, h] = sum over contributing s of a_s * enc[b,s,h]
    const int cnt = scnt;
    float4 acc = make_float4(0.f, 0.f, 0.f, 0.f);
    for (int j = 0; j < cnt; ++j) {
        const int s = slist[j];
        const float a = sp[s] * inv;
        const float4 v =
            ((const float4*)(enc + ((size_t)b * S_ + s) * H_))[tid];
        acc.x += a * v.x; acc.y += a * v.y;
        acc.z += a * v.z; acc.w += a * v.w;
    }
    ((float4*)(out_ctx + (size_t)b * H_))[tid] = acc;
}

extern "C" void kernel_launch(void* const* d_in, const int* in_sizes, int n_in,
                              void* d_out, int out_size, void* d_ws, size_t ws_size,
                              hipStream_t stream) {
    const float* dec = (const float*)d_in[0];   // [32,1024]
    const float* enc = (const float*)d_in[1];   // [32,4096,1024]
    const float* W   = (const float*)d_in[2];   // [1024,1024]
    const int*   pos = (const int*)d_in[3];     // scalar

    float* out      = (float*)d_out;
    float* out_ctx  = out;                      // [32,1,1024] -> 32768
    float* out_att  = out + (size_t)B_ * H_;    // [32,4096,1] -> 131072

    float* proj   = (float*)d_ws;               // 32768 floats (128 KB)
    float* energy = proj + (size_t)B_ * H_;     // 131072 floats (512 KB)

    proj_kernel<<<256, 256, 0, stream>>>(dec, W, proj);
    energy_kernel<<<2048, 256, 0, stream>>>(enc, proj, energy);
    softmax_ctx_kernel<<<32, 256, 0, stream>>>(enc, energy, pos, out_ctx, out_att);
}